// Round 3
// baseline (81.387 us; speedup 1.0000x reference)
//
#include <hip/hip_runtime.h>

// PointCloudRenderer — single fused kernel, tile-gather formulation.
// RADIUS=0.005 NDC = 0.32 px < 0.5 px => each point covers AT MOST ONE pixel
// center (validated: round-2 scatter version passed with absmax 0.0).
// One block per 16x16 pixel tile: re-project all P points (8/thread, ~20 FLOP
// each — cheaper than a global-memory round trip), append in-tile hits to an
// LDS candidate list, then each thread composites its own pixel with a
// register K-list ordered lexicographically by (z, point_idx) to reproduce
// top_k's deterministic tie-breaking regardless of LDS-atomic arrival order.

constexpr int   IMGC  = 128;
constexpr int   HWC   = IMGC * IMGC;
constexpr int   KTOP  = 10;
constexpr int   TILE  = 16;
constexpr int   TPB   = 256;           // one thread per tile pixel
constexpr int   CAPT  = 768;           // LDS candidate cap (expected peak ~120)
constexpr float BIGF  = 1e10f;
constexpr float R2C   = 2.5e-05f;      // float32(0.005^2)
constexpr float SCALE = 0.015625f;     // 2/128, exact power of two

__launch_bounds__(TPB)
__global__ void render_kernel(const float* __restrict__ points,
                              const float* __restrict__ feats,
                              const float* __restrict__ camR,
                              const float* __restrict__ camT,
                              const float* __restrict__ fptr,
                              float* __restrict__ out,
                              int B, int P)
{
    __shared__ float4 cand[CAPT];      // {px, py, z, bitcast(point_idx)}
    __shared__ int    cnt;

    const int tilesPerB = (IMGC / TILE) * (IMGC / TILE);   // 64
    const int b    = blockIdx.x / tilesPerB;
    const int tile = blockIdx.x - b * tilesPerB;
    const int r0   = (tile >> 3) * TILE;
    const int c0   = (tile & 7) * TILE;

    if (threadIdx.x == 0) cnt = 0;
    __syncthreads();

    const float* R = camR + 9 * b;
    const float* t = camT + 3 * b;
    const float  f = fptr[0];
    const float R00=R[0],R01=R[1],R02=R[2],
                R10=R[3],R11=R[4],R12=R[5],
                R20=R[6],R21=R[7],R22=R[8];
    const float t0=t[0], t1=t[1], t2=t[2];

    // ---- filter phase: 8 points per thread ----
    for (int p = threadIdx.x; p < P; p += TPB) {
        const float* pp = points + ((size_t)b * P + p) * 3;
        float p0 = pp[0], p1 = pp[1], p2 = pp[2];
        // row-vector convention: cam_j = sum_i p_i * R[i][j] + t[j]
        float x = p0*R00 + p1*R10 + p2*R20 + t0;
        float y = p0*R01 + p1*R11 + p2*R21 + t1;
        float z = p0*R02 + p1*R12 + p2*R22 + t2;
        // exact numpy-match: (f*x)/z + cx, no contraction
        float px = __fadd_rn(__fdiv_rn(__fmul_rn(f, x), z), 64.0f);
        float py = __fadd_rn(__fdiv_rn(__fmul_rn(f, y), z), 64.0f);
        // unique candidate pixel = floor; in-tile test (NaN-safe: compares false)
        float fx = floorf(px), fy = floorf(py);
        if (!(fx >= (float)c0 && fx < (float)(c0 + TILE) &&
              fy >= (float)r0 && fy < (float)(r0 + TILE))) continue;
        float gx = fx + 0.5f, gy = fy + 0.5f;
        // identical arithmetic to the reference's hit test
        float dx = __fmul_rn(__fsub_rn(px, gx), SCALE);
        float dy = __fmul_rn(__fsub_rn(py, gy), SCALE);
        float d2 = __fadd_rn(__fmul_rn(dx, dx), __fmul_rn(dy, dy));
        if (d2 < R2C && z > 1e-3f) {
            int s = atomicAdd(&cnt, 1);
            if (s < CAPT) cand[s] = make_float4(px, py, z, __int_as_float(p));
        }
    }
    __syncthreads();
    const int n = cnt < CAPT ? cnt : CAPT;

    // ---- composite phase: one thread per pixel ----
    const int   col = c0 + (threadIdx.x & 15);
    const int   row = r0 + (threadIdx.x >> 4);
    const float gx  = col + 0.5f, gy = row + 0.5f;

    float zk[KTOP], d2k[KTOP];
    int   ik[KTOP];
#pragma unroll
    for (int j = 0; j < KTOP; ++j) { zk[j] = BIGF; d2k[j] = 0.0f; ik[j] = 0x7fffffff; }

    for (int j = 0; j < n; ++j) {
        float4 v = cand[j];            // wave-uniform LDS broadcast, conflict-free
        if ((int)floorf(v.x) != col || (int)floorf(v.y) != row) continue;
        int pidx = __float_as_int(v.w);
        // lexicographic (z, idx) insertion == stable top_k selection
        if (v.z < zk[KTOP-1] || (v.z == zk[KTOP-1] && pidx < ik[KTOP-1])) {
            float dx = __fmul_rn(__fsub_rn(v.x, gx), SCALE);
            float dy = __fmul_rn(__fsub_rn(v.y, gy), SCALE);
            float d2 = __fadd_rn(__fmul_rn(dx, dx), __fmul_rn(dy, dy));
            zk[KTOP-1] = v.z; d2k[KTOP-1] = d2; ik[KTOP-1] = pidx;
#pragma unroll
            for (int q = KTOP-1; q > 0; --q) {     // unrolled: compile-time indices
                bool sw = (zk[q] < zk[q-1]) ||
                          (zk[q] == zk[q-1] && ik[q] < ik[q-1]);
                if (sw) {
                    float tz = zk[q];  zk[q]  = zk[q-1];  zk[q-1]  = tz;
                    float td = d2k[q]; d2k[q] = d2k[q-1]; d2k[q-1] = td;
                    int   ti = ik[q];  ik[q]  = ik[q-1];  ik[q-1]  = ti;
                }
            }
        }
    }

    // front-to-back alpha compositing: w_k = a_k * prod_{j<k}(1 - a_j)
    float T = 1.0f, ccr = 0.0f, ccg = 0.0f, ccb = 0.0f;
#pragma unroll
    for (int j = 0; j < KTOP; ++j) {
        if (zk[j] < 0.5f * BIGF) {
            float a = 1.0f - d2k[j] / R2C;
            a = fminf(fmaxf(a, 0.0f), 1.0f);
            float w = a * T;
            const float* ft = feats + ((size_t)b * P + ik[j]) * 3;
            ccr += w * ft[0]; ccg += w * ft[1]; ccb += w * ft[2];
            T *= (1.0f - a);
        }
    }

    const int pix = row * IMGC + col;
    float* img = out + (size_t)(b * HWC + pix) * 3;
    img[0] = ccr; img[1] = ccg; img[2] = ccb;
    // depth image: nearest z or -1 background
    out[(size_t)B * HWC * 3 + (size_t)b * HWC + pix] =
        (zk[0] < 0.5f * BIGF) ? zk[0] : -1.0f;
}

extern "C" void kernel_launch(void* const* d_in, const int* in_sizes, int n_in,
                              void* d_out, int out_size, void* d_ws, size_t ws_size,
                              hipStream_t stream) {
    const float* points = (const float*)d_in[0];
    const float* feats  = (const float*)d_in[1];
    const float* camR   = (const float*)d_in[2];
    const float* camT   = (const float*)d_in[3];
    const float* fptr   = (const float*)d_in[4];

    const int B = in_sizes[3] / 3;        // cam_t is [B,3]
    const int P = in_sizes[0] / (3 * B);  // points is [B,P,3]

    const int tilesPerB = (IMGC / TILE) * (IMGC / TILE);   // 64
    render_kernel<<<B * tilesPerB, TPB, 0, stream>>>(
        points, feats, camR, camT, fptr, (float*)d_out, B, P);
}